// Round 2
// baseline (125.770 us; speedup 1.0000x reference)
//
#include <hip/hip_runtime.h>
#include <stdint.h>

// Problem constants (B=1, L=256, C=128, N=4, TN=4)
#define LLTOT 65536
#define CDIM  128
#define TPIX  32
#define NBLK  (LLTOT / TPIX)   // 2048

typedef float f32x4 __attribute__((ext_vector_type(4)));
typedef short s16x8 __attribute__((ext_vector_type(8)));

#define MFMA16(a, b, c) __builtin_amdgcn_mfma_f32_16x16x32_bf16((a), (b), (c), 0, 0, 0)

// ws16 (uint16 units) layout:
//   [0)       Weff_b  [32][128] bf16   (24 real rows, rest zero)
//   [4096)    W1g_b   [512][128] bf16  (W1 * ln_g per column)
//   [69632)   W2_b    [128][512] bf16
//   [135168)  f32 region: hA[512] (b1 + W1@ln_b), W1gs[512] (row sums of W1*g)
#define WEFF16 0
#define W1G16  4096
#define W2_16  69632
#define F32OFF 135168

__device__ __forceinline__ unsigned short f2bf(float f) {
    union { float f; uint32_t u; } v; v.f = f;
    uint32_t u = v.u;
    return (unsigned short)((u + 0x7FFFu + ((u >> 16) & 1u)) >> 16);
}

__global__ void prep_kernel(const float* __restrict__ Wpre, const float* __restrict__ Wpost,
                            const float* __restrict__ Wres, const float* __restrict__ W1,
                            const float* __restrict__ W2, const float* __restrict__ ln_g,
                            const float* __restrict__ ln_b, const float* __restrict__ b1,
                            unsigned short* __restrict__ ws16) {
    int b = blockIdx.x, t = threadIdx.x;
    if (b == 264) {
        // per-row folded scalars for GEMM1
        int j = t;   // 512 threads
        float sg = 0.f, sb = 0.f;
        const float* row = W1 + j * 128;
        #pragma unroll 4
        for (int c = 0; c < 128; c += 4) {
            float4 wv = *(const float4*)(row + c);
            float4 gv = *(const float4*)(ln_g + c);
            float4 bv = *(const float4*)(ln_b + c);
            sg += wv.x*gv.x + wv.y*gv.y + wv.z*gv.z + wv.w*gv.w;
            sb += wv.x*bv.x + wv.y*bv.y + wv.z*bv.z + wv.w*bv.w;
        }
        float* f = (float*)(ws16 + F32OFF);
        f[j]       = b1[j] + sb;   // hA
        f[512 + j] = sg;           // W1gs
        return;
    }
    int idx = b * 512 + t;
    if (idx < 4096) {
        int o = idx >> 7, c = idx & 127;
        float v = 0.f;
        if (o < 4)        v = Wpre[o*512+c] + Wpre[o*512+128+c] + Wpre[o*512+256+c] + Wpre[o*512+384+c];
        else if (o < 8)   { int j = o - 4;  v = Wpost[j*512+c] + Wpost[j*512+128+c] + Wpost[j*512+256+c] + Wpost[j*512+384+c]; }
        else if (o < 24)  { int j = o - 8;  v = Wres[j*512+c] + Wres[j*512+128+c] + Wres[j*512+256+c] + Wres[j*512+384+c]; }
        ws16[idx] = f2bf(v);
    } else if (idx < 69632) {
        int r = idx - 4096; int c = r & 127;
        ws16[idx] = f2bf(W1[r] * ln_g[c]);
    } else if (idx < 135168) {
        ws16[idx] = f2bf(W2[idx - 69632]);
    }
}

__global__ void __launch_bounds__(512, 4) fused_kernel(
    const float* __restrict__ p, const float* __restrict__ p_mask,
    const float* __restrict__ b_pre, const float* __restrict__ b_post, const float* __restrict__ b_res,
    const float* __restrict__ a_pre, const float* __restrict__ a_post, const float* __restrict__ a_res,
    const float* __restrict__ b2,
    const unsigned short* __restrict__ ws16, float* __restrict__ out)
{
    __shared__ __align__(16) unsigned short p_bf[TPIX * CDIM];   // 8 KB  bf16 p, swizzled
    __shared__ __align__(16) unsigned short h_s[TPIX * 512];     // 32 KB bf16 relu(h), swizzled
    __shared__ __align__(16) float          D_s[TPIX * CDIM];    // 16 KB GEMM2 out, swizzled
    __shared__ __align__(16) float          y_s[TPIX * 32];      // 4 KB  routing logits (rms-unscaled)
    __shared__ __align__(16) float hA_s[512], W1gs_s[512];       // 4 KB
    __shared__ __align__(16) float b2_s[CDIM];
    __shared__ float rms_s[TPIX], mean_s[TPIX], var_s[TPIX], mask_s[TPIX];
    __shared__ float sistd_s[TPIX], muistd_s[TPIX];
    __shared__ float A_s[TPIX * 4], B_s[TPIX * 4];
    __shared__ float bpre_s[4], bpost_s[4], bres_s[16];

    const int t = threadIdx.x;
    const int base = blockIdx.x * TPIX;
    const int w = t >> 6, l = t & 63, lr = l & 15, lk = l >> 4;

    // ---- phase 1: load p (f32) -> stats in regs -> bf16 LDS; stage params ----
    {
        const float4* pg = (const float4*)(p + (size_t)base * CDIM);
        #pragma unroll
        for (int q = 0; q < 2; ++q) {
            int chunk = t + q * 512;          // 1024 float4s
            int pix = chunk >> 5, c4 = chunk & 31;
            float4 v = pg[chunk];
            float s  = v.x + v.y + v.z + v.w;
            float ss = v.x*v.x + v.y*v.y + v.z*v.z + v.w*v.w;
            s += __shfl_xor(s, 1);  ss += __shfl_xor(ss, 1);
            s += __shfl_xor(s, 2);  ss += __shfl_xor(ss, 2);
            s += __shfl_xor(s, 4);  ss += __shfl_xor(ss, 4);
            s += __shfl_xor(s, 8);  ss += __shfl_xor(ss, 8);
            s += __shfl_xor(s, 16); ss += __shfl_xor(ss, 16);
            if ((t & 31) == 0) {
                float mu = s * (1.f / 128.f), mq = ss * (1.f / 128.f);
                rms_s[pix]  = rsqrtf(mq + 1.1920929e-07f);
                mean_s[pix] = mu;
                var_s[pix]  = mq - mu * mu;
            }
            uint32_t lo = f2bf(v.x) | ((uint32_t)f2bf(v.y) << 16);
            uint32_t hi = f2bf(v.z) | ((uint32_t)f2bf(v.w) << 16);
            uint32_t off = (uint32_t)(pix * 256 + c4 * 8) ^ ((pix & 7) << 4);
            *(uint2*)((char*)p_bf + off) = make_uint2(lo, hi);
        }
        const float* fws = (const float*)(ws16 + F32OFF);
        if (t < 128)       ((float4*)hA_s)[t]         = ((const float4*)fws)[t];
        else if (t < 256)  ((float4*)W1gs_s)[t - 128] = ((const float4*)(fws + 512))[t - 128];
        else if (t < 288)  ((float4*)b2_s)[t - 256]   = ((const float4*)b2)[t - 256];
        else if (t < 320)  mask_s[t - 288] = p_mask[base + (t - 288)];
        else if (t < 336)  bres_s[t - 320] = b_res[t - 320];
        else if (t < 340)  bpre_s[t - 336] = b_pre[t - 336];
        else if (t < 344)  bpost_s[t - 340] = b_post[t - 340];
    }
    __syncthreads();

    // ---- phase 2: GEMM1 (all waves, 64 j-rows each) + routing GEMM (wave 0) ----
    f32x4 acc[4][2] = {};
    {
        f32x4 racc[2][2] = {};
        const unsigned short* W1b = ws16 + W1G16;
        #pragma unroll
        for (int kk = 0; kk < 4; ++kk) {
            s16x8 bfr[2];
            #pragma unroll
            for (int it = 0; it < 2; ++it) {
                int row = it * 16 + lr;
                uint32_t off = (uint32_t)(row * 256 + kk * 64 + lk * 16) ^ ((row & 7) << 4);
                bfr[it] = *(const s16x8*)((const char*)p_bf + off);
            }
            #pragma unroll
            for (int jt = 0; jt < 4; ++jt) {
                int j = w * 64 + jt * 16 + lr;
                s16x8 a = *(const s16x8*)((const char*)W1b + j * 256 + kk * 64 + lk * 16);
                acc[jt][0] = MFMA16(a, bfr[0], acc[jt][0]);
                acc[jt][1] = MFMA16(a, bfr[1], acc[jt][1]);
            }
            if (w == 0) {
                #pragma unroll
                for (int jt = 0; jt < 2; ++jt) {
                    int o = jt * 16 + lr;
                    s16x8 a = *(const s16x8*)((const char*)ws16 + o * 256 + kk * 64 + lk * 16);
                    racc[jt][0] = MFMA16(a, bfr[0], racc[jt][0]);
                    racc[jt][1] = MFMA16(a, bfr[1], racc[jt][1]);
                }
            }
        }
        // ---- wave 0: routing logits -> activations -> Sinkhorn -> per-pixel scalars ----
        if (w == 0) {
            #pragma unroll
            for (int jt = 0; jt < 2; ++jt)
                #pragma unroll
                for (int it = 0; it < 2; ++it)
                    *(f32x4*)(y_s + (it * 16 + lr) * 32 + jt * 16 + lk * 4) = racc[jt][it];
            asm volatile("s_waitcnt lgkmcnt(0)" ::: "memory");
            float apre = a_pre[0], apost = a_post[0], ares = a_res[0];
            #pragma unroll 1
            for (int hh = 0; hh < 2; ++hh) {
                int pix = (l >> 2) + hh * 16, m = l & 3;
                float rv = rms_s[pix];
                const float* yp = y_s + pix * 32;
                float hpre = 1.f / (1.f + expf(-(apre * tanhf(rv * yp[m]) + bpre_s[m])));
                float sp = hpre;
                sp += __shfl_xor(sp, 1); sp += __shfl_xor(sp, 2);
                float hp = 2.f / (1.f + expf(-(apost * tanhf(rv * yp[4 + m]) + bpost_s[m])));
                float M0 = expf(ares * tanhf(rv * yp[8 + m*4 + 0]) + bres_s[m*4 + 0]);
                float M1 = expf(ares * tanhf(rv * yp[8 + m*4 + 1]) + bres_s[m*4 + 1]);
                float M2 = expf(ares * tanhf(rv * yp[8 + m*4 + 2]) + bres_s[m*4 + 2]);
                float M3 = expf(ares * tanhf(rv * yp[8 + m*4 + 3]) + bres_s[m*4 + 3]);
                #pragma unroll 1
                for (int it2 = 0; it2 < 20; ++it2) {
                    float ri = __builtin_amdgcn_rcpf(M0 + M1 + M2 + M3);
                    M0 *= ri; M1 *= ri; M2 *= ri; M3 *= ri;
                    float c0 = M0, c1 = M1, c2 = M2, c3 = M3;
                    c0 += __shfl_xor(c0, 1); c1 += __shfl_xor(c1, 1); c2 += __shfl_xor(c2, 1); c3 += __shfl_xor(c3, 1);
                    c0 += __shfl_xor(c0, 2); c1 += __shfl_xor(c1, 2); c2 += __shfl_xor(c2, 2); c3 += __shfl_xor(c3, 2);
                    M0 *= __builtin_amdgcn_rcpf(c0); M1 *= __builtin_amdgcn_rcpf(c1);
                    M2 *= __builtin_amdgcn_rcpf(c2); M3 *= __builtin_amdgcn_rcpf(c3);
                }
                float r = M0 + M1 + M2 + M3;
                float istd = rsqrtf(sp * sp * var_s[pix] + 1e-5f);
                A_s[pix * 4 + m] = r + hp * sp;
                B_s[pix * 4 + m] = hp * mask_s[pix];
                if (m == 0) { sistd_s[pix] = sp * istd; muistd_s[pix] = sp * mean_s[pix] * istd; }
            }
        }
    }
    __syncthreads();

    // ---- phase 3: apply folded-LN scalars + bias + relu -> bf16 h_s ----
    {
        #pragma unroll
        for (int jt = 0; jt < 4; ++jt) {
            int j0 = w * 64 + jt * 16 + lk * 4;
            float wg0 = W1gs_s[j0],   wg1 = W1gs_s[j0+1], wg2 = W1gs_s[j0+2], wg3 = W1gs_s[j0+3];
            float ha0 = hA_s[j0],     ha1 = hA_s[j0+1],   ha2 = hA_s[j0+2],   ha3 = hA_s[j0+3];
            #pragma unroll
            for (int it = 0; it < 2; ++it) {
                int i = it * 16 + lr;
                float si = sistd_s[i], mi = muistd_s[i];
                f32x4 v = acc[jt][it];
                float h0 = fmaxf(fmaf(si, v[0], fmaf(-mi, wg0, ha0)), 0.f);
                float h1 = fmaxf(fmaf(si, v[1], fmaf(-mi, wg1, ha1)), 0.f);
                float h2 = fmaxf(fmaf(si, v[2], fmaf(-mi, wg2, ha2)), 0.f);
                float h3 = fmaxf(fmaf(si, v[3], fmaf(-mi, wg3, ha3)), 0.f);
                uint32_t u01 = f2bf(h0) | ((uint32_t)f2bf(h1) << 16);
                uint32_t u23 = f2bf(h2) | ((uint32_t)f2bf(h3) << 16);
                uint32_t off = (uint32_t)(i * 1024 + j0 * 2) ^ ((i & 7) << 4);
                *(uint2*)((char*)h_s + off) = make_uint2(u01, u23);
            }
        }
    }
    __syncthreads();

    // ---- phase 4: GEMM2  D[c,i] = W2[c,:] . h[i,:]  (wave w owns c-tile w) ----
    {
        const unsigned short* W2b = ws16 + W2_16;
        f32x4 acc2[2] = {};
        int c = w * 16 + lr;
        #pragma unroll 4
        for (int kk = 0; kk < 16; ++kk) {
            s16x8 a = *(const s16x8*)((const char*)W2b + c * 1024 + kk * 64 + lk * 16);
            #pragma unroll
            for (int it = 0; it < 2; ++it) {
                int i = it * 16 + lr;
                uint32_t off = (uint32_t)(i * 1024 + kk * 64 + lk * 16) ^ ((i & 7) << 4);
                s16x8 b = *(const s16x8*)((const char*)h_s + off);
                acc2[it] = MFMA16(a, b, acc2[it]);
            }
        }
        #pragma unroll
        for (int it = 0; it < 2; ++it) {
            int i = it * 16 + lr;
            uint32_t off = (uint32_t)(i * 512 + (w * 16 + lk * 4) * 4) ^ ((i & 7) << 4);
            *(f32x4*)((char*)D_s + off) = acc2[it];
        }
    }
    __syncthreads();

    // ---- phase 5: epilogue  out[i,m,c] = A_im*p[c] + B_im*(D+b2) ----
    {
        float4* og = (float4*)(out + (size_t)base * 512);
        #pragma unroll 2
        for (int q = 0; q < 8; ++q) {
            int idx = t + q * 512;            // 4096 float4s
            int pix = idx >> 7, rem = idx & 127;
            int m = rem >> 5, c4 = rem & 31;
            uint32_t poff = (uint32_t)(pix * 256 + c4 * 8) ^ ((pix & 7) << 4);
            uint2 pb = *(const uint2*)((const char*)p_bf + poff);
            float p0 = __uint_as_float(pb.x << 16);
            float p1 = __uint_as_float(pb.x & 0xffff0000u);
            float p2 = __uint_as_float(pb.y << 16);
            float p3 = __uint_as_float(pb.y & 0xffff0000u);
            uint32_t doff = (uint32_t)(pix * 512 + c4 * 16) ^ ((pix & 7) << 4);
            f32x4 d = *(const f32x4*)((const char*)D_s + doff);
            float Av = A_s[pix * 4 + m], Bv = B_s[pix * 4 + m];
            int c0 = c4 * 4;
            float4 o;
            o.x = Av * p0 + Bv * (d[0] + b2_s[c0]);
            o.y = Av * p1 + Bv * (d[1] + b2_s[c0 + 1]);
            o.z = Av * p2 + Bv * (d[2] + b2_s[c0 + 2]);
            o.w = Av * p3 + Bv * (d[3] + b2_s[c0 + 3]);
            og[idx] = o;
        }
    }
}

extern "C" void kernel_launch(void* const* d_in, const int* in_sizes, int n_in,
                              void* d_out, int out_size, void* d_ws, size_t ws_size,
                              hipStream_t stream) {
    const float* p      = (const float*)d_in[0];
    const float* p_mask = (const float*)d_in[1];
    const float* W_pre  = (const float*)d_in[2];
    const float* W_post = (const float*)d_in[3];
    const float* W_res  = (const float*)d_in[4];
    const float* b_pre  = (const float*)d_in[5];
    const float* b_post = (const float*)d_in[6];
    const float* b_res  = (const float*)d_in[7];
    const float* a_pre  = (const float*)d_in[8];
    const float* a_post = (const float*)d_in[9];
    const float* a_res  = (const float*)d_in[10];
    const float* ln_g   = (const float*)d_in[11];
    const float* ln_b   = (const float*)d_in[12];
    const float* W1     = (const float*)d_in[13];
    const float* b1     = (const float*)d_in[14];
    const float* W2     = (const float*)d_in[15];
    const float* b2     = (const float*)d_in[16];
    unsigned short* wsb = (unsigned short*)d_ws;
    float* out = (float*)d_out;

    prep_kernel<<<265, 512, 0, stream>>>(W_pre, W_post, W_res, W1, W2, ln_g, ln_b, b1, wsb);
    fused_kernel<<<NBLK, 512, 0, stream>>>(p, p_mask, b_pre, b_post, b_res,
                                           a_pre, a_post, a_res, b2, wsb, out);
}

// Round 3
// 105.295 us; speedup vs baseline: 1.1944x; 1.1944x over previous
//
#include <hip/hip_runtime.h>
#include <stdint.h>

// Problem constants (B=1, L=256, C=128, N=4, TN=4)
#define LLTOT 65536
#define CDIM  128
#define TPIX  32
#define NBLK  (LLTOT / TPIX)   // 2048

typedef float f32x4 __attribute__((ext_vector_type(4)));
typedef short s16x8 __attribute__((ext_vector_type(8)));

#define MFMA16(a, b, c) __builtin_amdgcn_mfma_f32_16x16x32_bf16((a), (b), (c), 0, 0, 0)

// ---- persistent device scratch (avoids ws_size uncertainty) ----
__device__ __align__(16) unsigned short g_weff[32 * 128];      // folded routing weights, bf16
__device__ __align__(16) unsigned short g_w1g[512 * 128];      // W1 * ln_g, bf16
__device__ __align__(16) unsigned short g_w2[128 * 512];       // W2, bf16
__device__ __align__(16) float g_hA[512];                      // b1 + W1 @ ln_b
__device__ __align__(16) float g_w1gs[512];                    // row sums of W1*ln_g
__device__ __align__(16) float g_sistd[LLTOT];                 // s_pre * istd
__device__ __align__(16) float g_muistd[LLTOT];                // s_pre * mean * istd
__device__ __align__(16) float g_A[LLTOT * 4];                 // r_m + hpost_m * s_pre
__device__ __align__(16) float g_Bc[LLTOT * 4];                // hpost_m * mask
__device__ __align__(16) unsigned short g_pbf[LLTOT * CDIM];   // bf16 p, pre-swizzled per 32-pixel tile

__device__ __forceinline__ unsigned short f2bf(float f) {
    union { float f; uint32_t u; } v; v.f = f;
    uint32_t u = v.u;
    return (unsigned short)((u + 0x7FFFu + ((u >> 16) & 1u)) >> 16);
}
__device__ __forceinline__ float bf2f(uint32_t lo16) { return __uint_as_float(lo16 << 16); }

__device__ __forceinline__ float fast_tanh(float x) {
    float cx = fminf(fmaxf(x, -10.f), 10.f);
    float e = __expf(2.f * cx);
    return (e - 1.f) * __builtin_amdgcn_rcpf(e + 1.f);
}
__device__ __forceinline__ float fast_sig(float z) {
    return __builtin_amdgcn_rcpf(1.f + __expf(-z));
}

// ---- prep: fold weights, convert to bf16 ----
__global__ void prep_kernel(const float* __restrict__ Wpre, const float* __restrict__ Wpost,
                            const float* __restrict__ Wres, const float* __restrict__ W1,
                            const float* __restrict__ W2, const float* __restrict__ ln_g,
                            const float* __restrict__ ln_b, const float* __restrict__ b1) {
    int b = blockIdx.x, t = threadIdx.x;
    if (b == 264) {
        int j = t;   // 512 threads
        float sg = 0.f, sb = 0.f;
        const float* row = W1 + j * 128;
        #pragma unroll 4
        for (int c = 0; c < 128; c += 4) {
            float4 wv = *(const float4*)(row + c);
            float4 gv = *(const float4*)(ln_g + c);
            float4 bv = *(const float4*)(ln_b + c);
            sg += wv.x*gv.x + wv.y*gv.y + wv.z*gv.z + wv.w*gv.w;
            sb += wv.x*bv.x + wv.y*bv.y + wv.z*bv.z + wv.w*bv.w;
        }
        g_hA[j]   = b1[j] + sb;
        g_w1gs[j] = sg;
        return;
    }
    int idx = b * 512 + t;
    if (idx < 4096) {
        int o = idx >> 7, c = idx & 127;
        float v = 0.f;
        if (o < 4)        v = Wpre[o*512+c] + Wpre[o*512+128+c] + Wpre[o*512+256+c] + Wpre[o*512+384+c];
        else if (o < 8)   { int j = o - 4;  v = Wpost[j*512+c] + Wpost[j*512+128+c] + Wpost[j*512+256+c] + Wpost[j*512+384+c]; }
        else if (o < 24)  { int j = o - 8;  v = Wres[j*512+c] + Wres[j*512+128+c] + Wres[j*512+256+c] + Wres[j*512+384+c]; }
        g_weff[idx] = f2bf(v);
    } else if (idx < 69632) {
        int r = idx - 4096; int c = r & 127;
        g_w1g[r] = f2bf(W1[r] * ln_g[c]);
    } else if (idx < 135168) {
        g_w2[idx - 69632] = f2bf(W2[idx - 69632]);
    }
}

// ---- K1: per-pixel routing + Sinkhorn -> scalars; also p -> bf16 (pre-swizzled global) ----
__global__ void __launch_bounds__(256) route_kernel(
    const float* __restrict__ p, const float* __restrict__ p_mask,
    const float* __restrict__ b_pre, const float* __restrict__ b_post, const float* __restrict__ b_res,
    const float* __restrict__ a_pre, const float* __restrict__ a_post, const float* __restrict__ a_res)
{
    __shared__ __align__(16) unsigned short p_bf[TPIX * CDIM];   // 8 KB swizzled bf16 p
    __shared__ __align__(16) float y_s[TPIX * 32];               // 4 KB routing logits
    __shared__ float rms_s[TPIX], mean_s[TPIX], var_s[TPIX], mask_s[TPIX];
    __shared__ float bpre_s[4], bpost_s[4], bres_s[16];

    const int t = threadIdx.x;
    const int base = blockIdx.x * TPIX;

    // phase 1: load p, register stats (32 lanes per pixel), bf16 convert -> LDS + global
    {
        const float4* pg = (const float4*)(p + (size_t)base * CDIM);
        char* pbfg = (char*)g_pbf + (size_t)blockIdx.x * 8192;
        #pragma unroll
        for (int q = 0; q < 4; ++q) {
            int idx = t + q * 256;            // 1024 float4
            int pix = idx >> 5, c4 = idx & 31;
            float4 v = pg[idx];
            float s  = v.x + v.y + v.z + v.w;
            float ss = v.x*v.x + v.y*v.y + v.z*v.z + v.w*v.w;
            s += __shfl_xor(s, 1);  ss += __shfl_xor(ss, 1);
            s += __shfl_xor(s, 2);  ss += __shfl_xor(ss, 2);
            s += __shfl_xor(s, 4);  ss += __shfl_xor(ss, 4);
            s += __shfl_xor(s, 8);  ss += __shfl_xor(ss, 8);
            s += __shfl_xor(s, 16); ss += __shfl_xor(ss, 16);
            if ((t & 31) == 0) {
                float mu = s * (1.f / 128.f), mq = ss * (1.f / 128.f);
                rms_s[pix]  = rsqrtf(mq + 1.1920929e-07f);
                mean_s[pix] = mu;
                var_s[pix]  = mq - mu * mu;
            }
            uint2 u;
            u.x = f2bf(v.x) | ((uint32_t)f2bf(v.y) << 16);
            u.y = f2bf(v.z) | ((uint32_t)f2bf(v.w) << 16);
            uint32_t off = (uint32_t)(pix * 256 + c4 * 8) ^ ((pix & 7) << 4);
            *(uint2*)((char*)p_bf + off) = u;
            *(uint2*)(pbfg + off) = u;
        }
        if (t < 32) mask_s[t] = p_mask[base + t];
        else if (t < 48) bres_s[t - 32] = b_res[t - 32];
        else if (t < 52) bpre_s[t - 48] = b_pre[t - 48];
        else if (t < 56) bpost_s[t - 52] = b_post[t - 52];
    }
    __syncthreads();

    // phase 2: routing mini-GEMM (wave 0): y[32 outs][32 pix]
    if (t < 64) {
        int lr = t & 15, lk = t >> 4;
        f32x4 racc[2][2] = {};
        #pragma unroll
        for (int kk = 0; kk < 4; ++kk) {
            s16x8 bfr[2];
            #pragma unroll
            for (int it = 0; it < 2; ++it) {
                int row = it * 16 + lr;
                uint32_t off = (uint32_t)(row * 256 + kk * 64 + lk * 16) ^ ((row & 7) << 4);
                bfr[it] = *(const s16x8*)((const char*)p_bf + off);
            }
            #pragma unroll
            for (int jt = 0; jt < 2; ++jt) {
                int o = jt * 16 + lr;
                s16x8 a = *(const s16x8*)((const char*)g_weff + o * 256 + kk * 64 + lk * 16);
                racc[jt][0] = MFMA16(a, bfr[0], racc[jt][0]);
                racc[jt][1] = MFMA16(a, bfr[1], racc[jt][1]);
            }
        }
        #pragma unroll
        for (int jt = 0; jt < 2; ++jt)
            #pragma unroll
            for (int it = 0; it < 2; ++it)
                *(f32x4*)(y_s + (it * 16 + lr) * 32 + jt * 16 + lk * 4) = racc[jt][it];
    }
    __syncthreads();

    // phase 3: activations + Sinkhorn (t < 128: pix = t>>2, m = t&3)
    if (t < 128) {
        int pix = t >> 2, m = t & 3;
        float apre = a_pre[0], apost = a_post[0], ares = a_res[0];
        float rv = rms_s[pix];
        const float* yp = y_s + pix * 32;
        float hpre = fast_sig(apre * fast_tanh(rv * yp[m]) + bpre_s[m]);
        float sp = hpre;
        sp += __shfl_xor(sp, 1); sp += __shfl_xor(sp, 2);
        float hp = 2.f * fast_sig(apost * fast_tanh(rv * yp[4 + m]) + bpost_s[m]);
        float M0 = __expf(ares * fast_tanh(rv * yp[8 + m*4 + 0]) + bres_s[m*4 + 0]);
        float M1 = __expf(ares * fast_tanh(rv * yp[8 + m*4 + 1]) + bres_s[m*4 + 1]);
        float M2 = __expf(ares * fast_tanh(rv * yp[8 + m*4 + 2]) + bres_s[m*4 + 2]);
        float M3 = __expf(ares * fast_tanh(rv * yp[8 + m*4 + 3]) + bres_s[m*4 + 3]);
        #pragma unroll 1
        for (int it2 = 0; it2 < 20; ++it2) {
            float ri = __builtin_amdgcn_rcpf(M0 + M1 + M2 + M3);
            M0 *= ri; M1 *= ri; M2 *= ri; M3 *= ri;
            float c0 = M0, c1 = M1, c2 = M2, c3 = M3;
            c0 += __shfl_xor(c0, 1); c1 += __shfl_xor(c1, 1); c2 += __shfl_xor(c2, 1); c3 += __shfl_xor(c3, 1);
            c0 += __shfl_xor(c0, 2); c1 += __shfl_xor(c1, 2); c2 += __shfl_xor(c2, 2); c3 += __shfl_xor(c3, 2);
            M0 *= __builtin_amdgcn_rcpf(c0); M1 *= __builtin_amdgcn_rcpf(c1);
            M2 *= __builtin_amdgcn_rcpf(c2); M3 *= __builtin_amdgcn_rcpf(c3);
        }
        float r = M0 + M1 + M2 + M3;
        int gp = base + pix;
        g_A [gp * 4 + m] = r + hp * sp;
        g_Bc[gp * 4 + m] = hp * mask_s[pix];
        if (m == 0) {
            float istd = rsqrtf(sp * sp * var_s[pix] + 1e-5f);
            g_sistd [gp] = sp * istd;
            g_muistd[gp] = sp * mean_s[pix] * istd;
        }
    }
}

// ---- K2: MLP (GEMM1 + GEMM2) + epilogue ----
__global__ void __launch_bounds__(512, 4) mlp_kernel(const float* __restrict__ b2,
                                                     float* __restrict__ out)
{
    __shared__ __align__(16) unsigned short p_bf[TPIX * CDIM];   // 8 KB bf16 p (swizzled <<4)
    __shared__ __align__(16) unsigned short h_s[TPIX * 512];     // 32 KB bf16 relu(h) (swizzled <<5)
    __shared__ __align__(16) unsigned short D_s[TPIX * CDIM];    // 8 KB bf16 D (swizzled <<4)
    __shared__ __align__(16) float hA_s[512], W1gs_s[512];
    __shared__ __align__(16) float b2_s[CDIM];
    __shared__ float si_s[TPIX], mi_s[TPIX];
    __shared__ float A_s[TPIX * 4], B_s[TPIX * 4];

    const int t = threadIdx.x;
    const int base = blockIdx.x * TPIX;
    const int w = t >> 6, l = t & 63, lr = l & 15, lk = l >> 4;

    // phase 1: pure copies (p tile pre-swizzled in global) + scalars
    {
        const uint4* src = (const uint4*)((const char*)g_pbf + (size_t)blockIdx.x * 8192);
        ((uint4*)p_bf)[t] = src[t];
        if (t < 128)       ((float4*)hA_s)[t]         = ((const float4*)g_hA)[t];
        else if (t < 256)  ((float4*)W1gs_s)[t - 128] = ((const float4*)g_w1gs)[t - 128];
        else if (t < 384)  A_s[t - 256] = g_A [base * 4 + (t - 256)];
        else               B_s[t - 384] = g_Bc[base * 4 + (t - 384)];
        if (t < 32)              si_s[t]      = g_sistd [base + t];
        else if (t < 64)         mi_s[t - 32] = g_muistd[base + (t - 32)];
        else if (t < 96)         ((float4*)b2_s)[t - 64] = ((const float4*)b2)[t - 64];
    }
    __syncthreads();

    // phase 2: GEMM1 (W1g[512,128] @ p^T) with one-step weight prefetch, then fold+relu -> h_s
    {
        f32x4 acc[4][2] = {};
        const char* wbase = (const char*)g_w1g + (w * 64 + lr) * 256 + lk * 16;
        s16x8 aw[4], awn[4];
        #pragma unroll
        for (int jt = 0; jt < 4; ++jt) aw[jt] = *(const s16x8*)(wbase + jt * 4096);
        #pragma unroll
        for (int kk = 0; kk < 4; ++kk) {
            s16x8 b0, b1;
            {
                uint32_t off = (uint32_t)(lr * 256 + kk * 64 + lk * 16) ^ ((lr & 7) << 4);
                b0 = *(const s16x8*)((const char*)p_bf + off);
            }
            {
                int row = 16 + lr;
                uint32_t off = (uint32_t)(row * 256 + kk * 64 + lk * 16) ^ ((row & 7) << 4);
                b1 = *(const s16x8*)((const char*)p_bf + off);
            }
            if (kk < 3) {
                #pragma unroll
                for (int jt = 0; jt < 4; ++jt) awn[jt] = *(const s16x8*)(wbase + jt * 4096 + (kk + 1) * 64);
            }
            #pragma unroll
            for (int jt = 0; jt < 4; ++jt) {
                acc[jt][0] = MFMA16(aw[jt], b0, acc[jt][0]);
                acc[jt][1] = MFMA16(aw[jt], b1, acc[jt][1]);
            }
            if (kk < 3) {
                #pragma unroll
                for (int jt = 0; jt < 4; ++jt) aw[jt] = awn[jt];
            }
        }
        #pragma unroll
        for (int jt = 0; jt < 4; ++jt) {
            int j0 = w * 64 + jt * 16 + lk * 4;
            float wg0 = W1gs_s[j0],   wg1 = W1gs_s[j0+1], wg2 = W1gs_s[j0+2], wg3 = W1gs_s[j0+3];
            float ha0 = hA_s[j0],     ha1 = hA_s[j0+1],   ha2 = hA_s[j0+2],   ha3 = hA_s[j0+3];
            #pragma unroll
            for (int it = 0; it < 2; ++it) {
                int i = it * 16 + lr;
                float si = si_s[i], mi = mi_s[i];
                f32x4 v = acc[jt][it];
                float h0 = fmaxf(fmaf(si, v[0], fmaf(-mi, wg0, ha0)), 0.f);
                float h1 = fmaxf(fmaf(si, v[1], fmaf(-mi, wg1, ha1)), 0.f);
                float h2 = fmaxf(fmaf(si, v[2], fmaf(-mi, wg2, ha2)), 0.f);
                float h3 = fmaxf(fmaf(si, v[3], fmaf(-mi, wg3, ha3)), 0.f);
                uint2 u;
                u.x = f2bf(h0) | ((uint32_t)f2bf(h1) << 16);
                u.y = f2bf(h2) | ((uint32_t)f2bf(h3) << 16);
                uint32_t off = (uint32_t)(i * 1024 + j0 * 2) ^ ((i & 7) << 5);
                *(uint2*)((char*)h_s + off) = u;
            }
        }
    }
    __syncthreads();

    // phase 3: GEMM2 (W2[128,512] @ h^T) with one-step weight prefetch -> bf16 D_s
    {
        const char* w2base = (const char*)g_w2 + (w * 16 + lr) * 1024 + lk * 16;
        f32x4 acc2[2] = {};
        s16x8 a = *(const s16x8*)(w2base);
        #pragma unroll
        for (int kk = 0; kk < 16; ++kk) {
            s16x8 b0, b1;
            {
                uint32_t off = (uint32_t)(lr * 1024 + kk * 64 + lk * 16) ^ ((lr & 7) << 5);
                b0 = *(const s16x8*)((const char*)h_s + off);
            }
            {
                int i = 16 + lr;
                uint32_t off = (uint32_t)(i * 1024 + kk * 64 + lk * 16) ^ ((i & 7) << 5);
                b1 = *(const s16x8*)((const char*)h_s + off);
            }
            s16x8 an;
            if (kk < 15) an = *(const s16x8*)(w2base + (kk + 1) * 64);
            acc2[0] = MFMA16(a, b0, acc2[0]);
            acc2[1] = MFMA16(a, b1, acc2[1]);
            if (kk < 15) a = an;
        }
        #pragma unroll
        for (int it = 0; it < 2; ++it) {
            int i = it * 16 + lr;
            int c0 = w * 16 + lk * 4;
            uint2 u;
            u.x = f2bf(acc2[it][0]) | ((uint32_t)f2bf(acc2[it][1]) << 16);
            u.y = f2bf(acc2[it][2]) | ((uint32_t)f2bf(acc2[it][3]) << 16);
            uint32_t off = (uint32_t)(i * 256 + c0 * 2) ^ ((i & 7) << 4);
            *(uint2*)((char*)D_s + off) = u;
        }
    }
    __syncthreads();

    // phase 4: epilogue  out[i,m,c] = A_im*p[c] + B_im*(D[i,c]+b2[c])
    {
        float4* og = (float4*)(out + (size_t)base * 512);
        #pragma unroll 2
        for (int q = 0; q < 8; ++q) {
            int idx = t + q * 512;            // 4096 float4
            int pix = idx >> 7, rem = idx & 127;
            int m = rem >> 5, c4 = rem & 31;
            int c0 = c4 * 4;
            uint32_t poff = (uint32_t)(pix * 256 + c4 * 8) ^ ((pix & 7) << 4);
            uint2 pb = *(const uint2*)((const char*)p_bf + poff);
            uint32_t doff = (uint32_t)(pix * 256 + c0 * 2) ^ ((pix & 7) << 4);
            uint2 db = *(const uint2*)((const char*)D_s + doff);
            float p0 = bf2f(pb.x & 0xffffu), p1 = __uint_as_float(pb.x & 0xffff0000u);
            float p2 = bf2f(pb.y & 0xffffu), p3 = __uint_as_float(pb.y & 0xffff0000u);
            float d0 = bf2f(db.x & 0xffffu), d1 = __uint_as_float(db.x & 0xffff0000u);
            float d2 = bf2f(db.y & 0xffffu), d3 = __uint_as_float(db.y & 0xffff0000u);
            float4 b2v = *(const float4*)(b2_s + c0);
            float Av = A_s[pix * 4 + m], Bv = B_s[pix * 4 + m];
            float4 o;
            o.x = Av * p0 + Bv * (d0 + b2v.x);
            o.y = Av * p1 + Bv * (d1 + b2v.y);
            o.z = Av * p2 + Bv * (d2 + b2v.z);
            o.w = Av * p3 + Bv * (d3 + b2v.w);
            og[idx] = o;
        }
    }
}

extern "C" void kernel_launch(void* const* d_in, const int* in_sizes, int n_in,
                              void* d_out, int out_size, void* d_ws, size_t ws_size,
                              hipStream_t stream) {
    const float* p      = (const float*)d_in[0];
    const float* p_mask = (const float*)d_in[1];
    const float* W_pre  = (const float*)d_in[2];
    const float* W_post = (const float*)d_in[3];
    const float* W_res  = (const float*)d_in[4];
    const float* b_pre  = (const float*)d_in[5];
    const float* b_post = (const float*)d_in[6];
    const float* b_res  = (const float*)d_in[7];
    const float* a_pre  = (const float*)d_in[8];
    const float* a_post = (const float*)d_in[9];
    const float* a_res  = (const float*)d_in[10];
    const float* ln_g   = (const float*)d_in[11];
    const float* ln_b   = (const float*)d_in[12];
    const float* W1     = (const float*)d_in[13];
    const float* b1     = (const float*)d_in[14];
    const float* W2     = (const float*)d_in[15];
    const float* b2     = (const float*)d_in[16];
    float* out = (float*)d_out;

    prep_kernel<<<265, 512, 0, stream>>>(W_pre, W_post, W_res, W1, W2, ln_g, ln_b, b1);
    route_kernel<<<NBLK, 256, 0, stream>>>(p, p_mask, b_pre, b_post, b_res,
                                           a_pre, a_post, a_res);
    mlp_kernel<<<NBLK, 512, 0, stream>>>(b2, out);
}